// Round 1
// baseline (756.735 us; speedup 1.0000x reference)
//
#include <hip/hip_runtime.h>
#include <math.h>

#define BROWS 4096
#define DIM   512
#define TI    128   // rows per block (i)
#define NPAIR 64    // pair-terms per block row (cols c0..c0+64 computed)
#define BK    32    // K-tile

// ---------------------------------------------------------------------------
// Kernel A: per-row stats. For row x: n = sqrt(sum x^2), inv = 1/max(n,1e-12),
// y = x*inv, s = sum y^2, r = sum y.  (4096 blocks x 256 threads, 2 elem/thr)
// ---------------------------------------------------------------------------
__global__ __launch_bounds__(256) void rowstats_kernel(
    const float* __restrict__ x, float* __restrict__ inv_out,
    float* __restrict__ s_out, float* __restrict__ r_out) {
  const int row = blockIdx.x;
  const int tid = threadIdx.x;
  const float* xr = x + (size_t)row * DIM;
  const float x0 = xr[tid];
  const float x1 = xr[tid + 256];

  __shared__ float sredA[4];
  __shared__ float sredB[4];
  __shared__ float sbcast;

  // reduce sum of squares
  float v = x0 * x0 + x1 * x1;
#pragma unroll
  for (int o = 32; o; o >>= 1) v += __shfl_down(v, o, 64);
  const int lane = tid & 63, wid = tid >> 6;
  if (lane == 0) sredA[wid] = v;
  __syncthreads();
  if (tid == 0) {
    const float ss = sredA[0] + sredA[1] + sredA[2] + sredA[3];
    sbcast = 1.0f / fmaxf(sqrtf(ss), 1e-12f);
  }
  __syncthreads();
  const float inv = sbcast;
  const float y0 = x0 * inv, y1 = x1 * inv;

  float sv = y0 * y0 + y1 * y1;
  float rv = y0 + y1;
#pragma unroll
  for (int o = 32; o; o >>= 1) {
    sv += __shfl_down(sv, o, 64);
    rv += __shfl_down(rv, o, 64);
  }
  __syncthreads();  // protect sredA reuse ordering (paranoia; separate arrays used anyway)
  if (lane == 0) { sredA[wid] = sv; sredB[wid] = rv; }
  __syncthreads();
  if (tid == 0) {
    inv_out[row] = inv;
    s_out[row] = sredA[0] + sredA[1] + sredA[2] + sredA[3];
    r_out[row] = sredB[0] + sredB[1] + sredB[2] + sredB[3];
  }
}

// ---------------------------------------------------------------------------
// Kernel B: fused double-Gram + distance + pair-term reduction.
// Grid: (4096/NPAIR=64, 4096/TI=32). Block 256 threads as 16x16.
// Thread (ty,tx): rows i0+ty*8..+7, cols c0+tx*4..+4 (5 cols, 4 pairs;
// thread column windows overlap by 1 so every pair is thread-local).
// ---------------------------------------------------------------------------
__global__ __launch_bounds__(256) void fused_kernel(
    const float* __restrict__ lowF, const float* __restrict__ embF,
    const float* __restrict__ inv_l, const float* __restrict__ s_l,
    const float* __restrict__ r_l,
    const float* __restrict__ inv_e, const float* __restrict__ s_e,
    const float* __restrict__ r_e,
    float* __restrict__ out) {
  __shared__ float sAl[BK][TI + 4];
  __shared__ float sAe[BK][TI + 4];
  __shared__ float sBl[BK][68];
  __shared__ float sBe[BK][68];
  __shared__ float sred[4];

  const int tid = threadIdx.x;
  const int tx = tid & 15, ty = tid >> 4;
  const int i0 = blockIdx.y * TI;
  const int c0 = blockIdx.x * NPAIR;

  float accl[8][5], acce[8][5];
#pragma unroll
  for (int u = 0; u < 8; ++u)
#pragma unroll
    for (int p = 0; p < 5; ++p) { accl[u][p] = 0.f; acce[u][p] = 0.f; }

  for (int k0 = 0; k0 < DIM; k0 += BK) {
    // ---- stage A tiles (128 rows x BK), normalize on the fly ----
#pragma unroll
    for (int t = 0; t < 4; ++t) {
      const int g = tid + t * 256;       // 0..1023
      const int r = g >> 3, c = g & 7;   // row, float4-chunk
      const int row = i0 + r;
      const float4 vl = *(const float4*)(lowF + (size_t)row * DIM + k0 + c * 4);
      const float4 ve = *(const float4*)(embF + (size_t)row * DIM + k0 + c * 4);
      const float il = inv_l[row], ie = inv_e[row];
      sAl[c * 4 + 0][r] = vl.x * il; sAl[c * 4 + 1][r] = vl.y * il;
      sAl[c * 4 + 2][r] = vl.z * il; sAl[c * 4 + 3][r] = vl.w * il;
      sAe[c * 4 + 0][r] = ve.x * ie; sAe[c * 4 + 1][r] = ve.y * ie;
      sAe[c * 4 + 2][r] = ve.z * ie; sAe[c * 4 + 3][r] = ve.w * ie;
    }
    // ---- stage B tiles (65 rows x BK) ----
    for (int g = tid; g < 65 * 8; g += 256) {
      const int r = g >> 3, c = g & 7;
      const int j = c0 + r;
      float4 vl = make_float4(0.f, 0.f, 0.f, 0.f);
      float4 ve = make_float4(0.f, 0.f, 0.f, 0.f);
      float il = 0.f, ie = 0.f;
      if (j < BROWS) {
        vl = *(const float4*)(lowF + (size_t)j * DIM + k0 + c * 4);
        ve = *(const float4*)(embF + (size_t)j * DIM + k0 + c * 4);
        il = inv_l[j]; ie = inv_e[j];
      }
      sBl[c * 4 + 0][r] = vl.x * il; sBl[c * 4 + 1][r] = vl.y * il;
      sBl[c * 4 + 2][r] = vl.z * il; sBl[c * 4 + 3][r] = vl.w * il;
      sBe[c * 4 + 0][r] = ve.x * ie; sBe[c * 4 + 1][r] = ve.y * ie;
      sBe[c * 4 + 2][r] = ve.z * ie; sBe[c * 4 + 3][r] = ve.w * ie;
    }
    __syncthreads();

#pragma unroll 4
    for (int kk = 0; kk < BK; ++kk) {
      float al[8], ae[8], bl[5], be[5];
#pragma unroll
      for (int u = 0; u < 8; ++u) {
        al[u] = sAl[kk][ty * 8 + u];
        ae[u] = sAe[kk][ty * 8 + u];
      }
#pragma unroll
      for (int p = 0; p < 5; ++p) {
        bl[p] = sBl[kk][tx * 4 + p];
        be[p] = sBe[kk][tx * 4 + p];
      }
#pragma unroll
      for (int u = 0; u < 8; ++u)
#pragma unroll
        for (int p = 0; p < 5; ++p) {
          accl[u][p] = fmaf(al[u], bl[p], accl[u][p]);
          acce[u][p] = fmaf(ae[u], be[p], acce[u][p]);
        }
    }
    __syncthreads();
  }

  // ---- epilogue: distances + pair terms ----
  const float epsterm = (float)DIM * 1e-6f * 1e-6f;  // D*EPS_PD^2
  float sjl[5], rjl[5], sje[5], rje[5];
#pragma unroll
  for (int p = 0; p < 5; ++p) {
    int j = c0 + tx * 4 + p;
    int jj = j < BROWS ? j : (BROWS - 1);  // clamp (masked below anyway)
    sjl[p] = s_l[jj]; rjl[p] = r_l[jj];
    sje[p] = s_e[jj]; rje[p] = r_e[jj];
  }

  float sum = 0.f;
#pragma unroll
  for (int u = 0; u < 8; ++u) {
    const int i = i0 + ty * 8 + u;
    if (i >= BROWS - 1) continue;  // rows 0..4094 only
    const float sil = s_l[i], ril = r_l[i];
    const float sie = s_e[i], rie = r_e[i];
    float dl[5], de[5];
#pragma unroll
    for (int p = 0; p < 5; ++p) {
      const float sql = sil + sjl[p] - 2.f * accl[u][p] +
                        2e-6f * (ril - rjl[p]) + epsterm;
      dl[p] = sqrtf(fmaxf(sql, 0.f));
      const float sqe = sie + sje[p] - 2.f * acce[u][p] +
                        2e-6f * (rie - rje[p]) + epsterm;
      de[p] = sqrtf(fmaxf(sqe, 0.f));
    }
#pragma unroll
    for (int p = 0; p < 4; ++p) {
      const int j = c0 + tx * 4 + p;
      if (j < BROWS - 2) {  // cols 0..4093 only
        const float a = dl[p] - dl[p + 1];
        const float b = de[p] - de[p + 1];
        const float coeff = (float)((a > 0.f) - (a < 0.f)) -
                            (float)((b > 0.f) - (b < 0.f));
        sum += coeff * (de[p + 1] - de[p]);
      }
    }
  }

  // ---- block reduce + atomic ----
#pragma unroll
  for (int o = 32; o; o >>= 1) sum += __shfl_down(sum, o, 64);
  const int lane = tid & 63, wid = tid >> 6;
  if (lane == 0) sred[wid] = sum;
  __syncthreads();
  if (tid == 0) {
    const float scale = 1.0f / ((float)(BROWS - 1) * (float)(BROWS - 2));
    atomicAdd(out, (sred[0] + sred[1] + sred[2] + sred[3]) * scale);
  }
}

extern "C" void kernel_launch(void* const* d_in, const int* in_sizes, int n_in,
                              void* d_out, int out_size, void* d_ws,
                              size_t ws_size, hipStream_t stream) {
  const float* low = (const float*)d_in[0];
  const float* emb = (const float*)d_in[1];
  // d_in[2] (id_numpy) is unused by the reference computation.
  float* out = (float*)d_out;

  // ws layout: 6 arrays x 4096 floats = 96 KB
  float* ws = (float*)d_ws;
  float* inv_l = ws;
  float* s_l = ws + 4096;
  float* r_l = ws + 8192;
  float* inv_e = ws + 12288;
  float* s_e = ws + 16384;
  float* r_e = ws + 20480;

  rowstats_kernel<<<BROWS, 256, 0, stream>>>(low, inv_l, s_l, r_l);
  rowstats_kernel<<<BROWS, 256, 0, stream>>>(emb, inv_e, s_e, r_e);
  hipMemsetAsync(d_out, 0, sizeof(float), stream);
  fused_kernel<<<dim3(BROWS / NPAIR, BROWS / TI), 256, 0, stream>>>(
      low, emb, inv_l, s_l, r_l, inv_e, s_e, r_e, out);
}

// Round 2
// 180.258 us; speedup vs baseline: 4.1981x; 4.1981x over previous
//
#include <hip/hip_runtime.h>
#include <hip/hip_bf16.h>
#include <math.h>

#define BROWS 4096
#define DIM   512

typedef float f32x4 __attribute__((ext_vector_type(4)));
typedef __bf16 bf16x8 __attribute__((ext_vector_type(8)));

// ===========================================================================
// PATH A (primary, needs ws >= 8.3 MB): bf16 MFMA
// ===========================================================================

// ---------------------------------------------------------------------------
// prep: per-row L2-normalize -> bf16 matrix Y, plus s = sum(y^2), r = sum(y)
// one block (256 thr) per row, 2 elems/thread.
// ---------------------------------------------------------------------------
__global__ __launch_bounds__(256) void prep_kernel(
    const float* __restrict__ x, __hip_bfloat16* __restrict__ Y,
    float* __restrict__ s_out, float* __restrict__ r_out) {
  const int row = blockIdx.x;
  const int tid = threadIdx.x;
  const float2 v = ((const float2*)(x + (size_t)row * DIM))[tid];

  __shared__ float sredA[4];
  __shared__ float sredB[4];
  __shared__ float sbcast;

  float ss = v.x * v.x + v.y * v.y;
#pragma unroll
  for (int o = 32; o; o >>= 1) ss += __shfl_down(ss, o, 64);
  const int lane = tid & 63, wid = tid >> 6;
  if (lane == 0) sredA[wid] = ss;
  __syncthreads();
  if (tid == 0)
    sbcast = 1.0f / fmaxf(sqrtf(sredA[0] + sredA[1] + sredA[2] + sredA[3]), 1e-12f);
  __syncthreads();
  const float inv = sbcast;
  const float y0 = v.x * inv, y1 = v.y * inv;

  __hip_bfloat162 h;
  h.x = __float2bfloat16(y0);
  h.y = __float2bfloat16(y1);
  ((__hip_bfloat162*)(Y + (size_t)row * DIM))[tid] = h;

  float sv = y0 * y0 + y1 * y1;
  float rv = y0 + y1;
#pragma unroll
  for (int o = 32; o; o >>= 1) {
    sv += __shfl_down(sv, o, 64);
    rv += __shfl_down(rv, o, 64);
  }
  __syncthreads();
  if (lane == 0) { sredA[wid] = sv; sredB[wid] = rv; }
  __syncthreads();
  if (tid == 0) {
    s_out[row] = sredA[0] + sredA[1] + sredA[2] + sredA[3];
    r_out[row] = sredB[0] + sredB[1] + sredB[2] + sredB[3];
  }
}

// ---------------------------------------------------------------------------
// MFMA fused kernel. Tile: M=128 rows(i) x N=80 cols(j); 79 pairs/block.
// Grid (52, 32). 4 waves; wave w: rows 32w..32w+31, all 80 cols, both mats.
// LDS per K-stage (BK=32): Alow[128][32] Aemb[128][32] Blow[80][32] Bemb[80][32]
// staged via global_load_lds width=16; frag layout = row-major [row][k].
// C frag mapping (verified m89/m91): col = lane&15, row = (lane>>4)*4 + reg.
// ---------------------------------------------------------------------------
#define ALOW_OFF 0
#define AEMB_OFF 4096
#define BLOW_OFF 8192
#define BEMB_OFF 10752
#define LDS_ELEMS 13312   // 26624 B
#define NCOLS 80
#define NPAIR 79

__global__ __launch_bounds__(256, 2) void fused_mfma_kernel(
    const __hip_bfloat16* __restrict__ Ylow,
    const __hip_bfloat16* __restrict__ Yemb,
    const float* __restrict__ s_l, const float* __restrict__ r_l,
    const float* __restrict__ s_e, const float* __restrict__ r_e,
    float* __restrict__ out) {
  __shared__ __align__(16) __hip_bfloat16 lds[LDS_ELEMS];
  __shared__ float sred[4];

  const int tid = threadIdx.x;
  const int lane = tid & 63;
  const int wid = tid >> 6;
  const int quad = lane >> 4;
  const int cpos = lane & 15;
  const int i0 = blockIdx.y * 128;
  const int c0 = blockIdx.x * NPAIR;

  f32x4 accl[2][5], acce[2][5];
#pragma unroll
  for (int u = 0; u < 2; ++u)
#pragma unroll
    for (int t = 0; t < 5; ++t) {
      accl[u][t] = (f32x4)(0.f);
      acce[u][t] = (f32x4)(0.f);
    }

  // constant LDS fragment offsets (elems)
  const int fragoff = cpos * 32 + quad * 8;
  const int arow = 32 * wid;

  for (int k0 = 0; k0 < DIM; k0 += 32) {
    // ---- stage: 1664 16B-chunks -> LDS. chunk c: row=c>>2, kchunk=c&3.
    // segments: [0,512) Alow, [512,1024) Aemb, [1024,1344) Blow, [1344,1664) Bemb
    for (int cb = wid * 64; cb < 1664; cb += 256) {
      const int c = cb + lane;
      const __hip_bfloat16* gp;
      if (cb < 512) {
        gp = Ylow + (size_t)(i0 + (c >> 2)) * DIM + k0 + ((c & 3) << 3);
      } else if (cb < 1024) {
        const int cc = c - 512;
        gp = Yemb + (size_t)(i0 + (cc >> 2)) * DIM + k0 + ((cc & 3) << 3);
      } else if (cb < 1344) {
        const int cc = c - 1024;
        const int gr = min(c0 + (cc >> 2), BROWS - 1);
        gp = Ylow + (size_t)gr * DIM + k0 + ((cc & 3) << 3);
      } else {
        const int cc = c - 1344;
        const int gr = min(c0 + (cc >> 2), BROWS - 1);
        gp = Yemb + (size_t)gr * DIM + k0 + ((cc & 3) << 3);
      }
      __builtin_amdgcn_global_load_lds(
          (const __attribute__((address_space(1))) void*)gp,
          (__attribute__((address_space(3))) void*)&lds[cb * 8], 16, 0, 0);
    }
    __syncthreads();

    // ---- frags + MFMA
    bf16x8 al[2], ae[2], bl[5], be[5];
#pragma unroll
    for (int u = 0; u < 2; ++u) {
      al[u] = *(const bf16x8*)&lds[ALOW_OFF + (arow + 16 * u) * 32 + fragoff];
      ae[u] = *(const bf16x8*)&lds[AEMB_OFF + (arow + 16 * u) * 32 + fragoff];
    }
#pragma unroll
    for (int t = 0; t < 5; ++t) {
      bl[t] = *(const bf16x8*)&lds[BLOW_OFF + (16 * t) * 32 + fragoff];
      be[t] = *(const bf16x8*)&lds[BEMB_OFF + (16 * t) * 32 + fragoff];
    }
#pragma unroll
    for (int u = 0; u < 2; ++u)
#pragma unroll
      for (int t = 0; t < 5; ++t) {
        accl[u][t] = __builtin_amdgcn_mfma_f32_16x16x32_bf16(al[u], bl[t], accl[u][t], 0, 0, 0);
        acce[u][t] = __builtin_amdgcn_mfma_f32_16x16x32_bf16(ae[u], be[t], acce[u][t], 0, 0, 0);
      }
    __syncthreads();
  }

  // ---- epilogue: distances + pair terms (pairs are lane-local via shfl)
  const float epsterm = (float)DIM * 1e-6f * 1e-6f;
  float sum = 0.f;
#pragma unroll
  for (int u = 0; u < 2; ++u) {
#pragma unroll
    for (int r = 0; r < 4; ++r) {
      const int i = i0 + arow + 16 * u + quad * 4 + r;
      const float sil = s_l[i], ril = r_l[i];
      const float sie = s_e[i], rie = r_e[i];
      float dl[5], de[5];
#pragma unroll
      for (int t = 0; t < 5; ++t) {
        const int j = min(c0 + 16 * t + cpos, BROWS - 1);
        const float sql = sil + s_l[j] - 2.f * accl[u][t][r] +
                          2e-6f * (ril - r_l[j]) + epsterm;
        dl[t] = sqrtf(fmaxf(sql, 0.f));
        const float sqe = sie + s_e[j] - 2.f * acce[u][t][r] +
                          2e-6f * (rie - r_e[j]) + epsterm;
        de[t] = sqrtf(fmaxf(sqe, 0.f));
      }
      const bool rowok = (i <= BROWS - 2);
#pragma unroll
      for (int t = 0; t < 5; ++t) {
        const int srcin = (lane & 48) | ((cpos + 1) & 15);
        const float dl_in = __shfl(dl[t], srcin, 64);
        const float de_in = __shfl(de[t], srcin, 64);
        float dl2, de2;
        if (t < 4) {
          const float dl_bd = __shfl(dl[t + 1], lane & 48, 64);
          const float de_bd = __shfl(de[t + 1], lane & 48, 64);
          dl2 = (cpos == 15) ? dl_bd : dl_in;
          de2 = (cpos == 15) ? de_bd : de_in;
        } else {
          dl2 = dl_in;
          de2 = de_in;
        }
        const int p = 16 * t + cpos;
        const int j = c0 + p;
        if (rowok && p < NPAIR && j <= BROWS - 3) {
          const float a = dl[t] - dl2;
          const float b = de[t] - de2;
          const float coeff = (float)((a > 0.f) - (a < 0.f)) -
                              (float)((b > 0.f) - (b < 0.f));
          sum += coeff * (de2 - de[t]);
        }
      }
    }
  }

#pragma unroll
  for (int o = 32; o; o >>= 1) sum += __shfl_down(sum, o, 64);
  if (lane == 0) sred[wid] = sum;
  __syncthreads();
  if (tid == 0) {
    const float scale = 1.0f / ((float)(BROWS - 1) * (float)(BROWS - 2));
    atomicAdd(out, (sred[0] + sred[1] + sred[2] + sred[3]) * scale);
  }
}

// ===========================================================================
// PATH B (fallback if ws too small): round-1 fp32 kernels (passed, 807 us)
// ===========================================================================
__global__ __launch_bounds__(256) void rowstats_kernel(
    const float* __restrict__ x, float* __restrict__ inv_out,
    float* __restrict__ s_out, float* __restrict__ r_out) {
  const int row = blockIdx.x;
  const int tid = threadIdx.x;
  const float* xr = x + (size_t)row * DIM;
  const float x0 = xr[tid];
  const float x1 = xr[tid + 256];
  __shared__ float sredA[4];
  __shared__ float sredB[4];
  __shared__ float sbcast;
  float v = x0 * x0 + x1 * x1;
#pragma unroll
  for (int o = 32; o; o >>= 1) v += __shfl_down(v, o, 64);
  const int lane = tid & 63, wid = tid >> 6;
  if (lane == 0) sredA[wid] = v;
  __syncthreads();
  if (tid == 0)
    sbcast = 1.0f / fmaxf(sqrtf(sredA[0] + sredA[1] + sredA[2] + sredA[3]), 1e-12f);
  __syncthreads();
  const float inv = sbcast;
  const float y0 = x0 * inv, y1 = x1 * inv;
  float sv = y0 * y0 + y1 * y1;
  float rv = y0 + y1;
#pragma unroll
  for (int o = 32; o; o >>= 1) {
    sv += __shfl_down(sv, o, 64);
    rv += __shfl_down(rv, o, 64);
  }
  __syncthreads();
  if (lane == 0) { sredA[wid] = sv; sredB[wid] = rv; }
  __syncthreads();
  if (tid == 0) {
    inv_out[row] = inv;
    s_out[row] = sredA[0] + sredA[1] + sredA[2] + sredA[3];
    r_out[row] = sredB[0] + sredB[1] + sredB[2] + sredB[3];
  }
}

__global__ __launch_bounds__(256) void fused_fp32_kernel(
    const float* __restrict__ lowF, const float* __restrict__ embF,
    const float* __restrict__ inv_l, const float* __restrict__ s_l,
    const float* __restrict__ r_l,
    const float* __restrict__ inv_e, const float* __restrict__ s_e,
    const float* __restrict__ r_e,
    float* __restrict__ out) {
  __shared__ float sAl[32][132];
  __shared__ float sAe[32][132];
  __shared__ float sBl[32][68];
  __shared__ float sBe[32][68];
  __shared__ float sred[4];
  const int tid = threadIdx.x;
  const int tx = tid & 15, ty = tid >> 4;
  const int i0 = blockIdx.y * 128;
  const int c0 = blockIdx.x * 64;
  float accl[8][5], acce[8][5];
#pragma unroll
  for (int u = 0; u < 8; ++u)
#pragma unroll
    for (int p = 0; p < 5; ++p) { accl[u][p] = 0.f; acce[u][p] = 0.f; }
  for (int k0 = 0; k0 < DIM; k0 += 32) {
#pragma unroll
    for (int t = 0; t < 4; ++t) {
      const int g = tid + t * 256;
      const int r = g >> 3, c = g & 7;
      const int row = i0 + r;
      const float4 vl = *(const float4*)(lowF + (size_t)row * DIM + k0 + c * 4);
      const float4 ve = *(const float4*)(embF + (size_t)row * DIM + k0 + c * 4);
      const float il = inv_l[row], ie = inv_e[row];
      sAl[c * 4 + 0][r] = vl.x * il; sAl[c * 4 + 1][r] = vl.y * il;
      sAl[c * 4 + 2][r] = vl.z * il; sAl[c * 4 + 3][r] = vl.w * il;
      sAe[c * 4 + 0][r] = ve.x * ie; sAe[c * 4 + 1][r] = ve.y * ie;
      sAe[c * 4 + 2][r] = ve.z * ie; sAe[c * 4 + 3][r] = ve.w * ie;
    }
    for (int g = tid; g < 65 * 8; g += 256) {
      const int r = g >> 3, c = g & 7;
      const int j = c0 + r;
      float4 vl = make_float4(0.f, 0.f, 0.f, 0.f);
      float4 ve = make_float4(0.f, 0.f, 0.f, 0.f);
      float il = 0.f, ie = 0.f;
      if (j < BROWS) {
        vl = *(const float4*)(lowF + (size_t)j * DIM + k0 + c * 4);
        ve = *(const float4*)(embF + (size_t)j * DIM + k0 + c * 4);
        il = inv_l[j]; ie = inv_e[j];
      }
      sBl[c * 4 + 0][r] = vl.x * il; sBl[c * 4 + 1][r] = vl.y * il;
      sBl[c * 4 + 2][r] = vl.z * il; sBl[c * 4 + 3][r] = vl.w * il;
      sBe[c * 4 + 0][r] = ve.x * ie; sBe[c * 4 + 1][r] = ve.y * ie;
      sBe[c * 4 + 2][r] = ve.z * ie; sBe[c * 4 + 3][r] = ve.w * ie;
    }
    __syncthreads();
#pragma unroll 4
    for (int kk = 0; kk < 32; ++kk) {
      float al[8], ae2[8], bl[5], be[5];
#pragma unroll
      for (int u = 0; u < 8; ++u) {
        al[u] = sAl[kk][ty * 8 + u];
        ae2[u] = sAe[kk][ty * 8 + u];
      }
#pragma unroll
      for (int p = 0; p < 5; ++p) {
        bl[p] = sBl[kk][tx * 4 + p];
        be[p] = sBe[kk][tx * 4 + p];
      }
#pragma unroll
      for (int u = 0; u < 8; ++u)
#pragma unroll
        for (int p = 0; p < 5; ++p) {
          accl[u][p] = fmaf(al[u], bl[p], accl[u][p]);
          acce[u][p] = fmaf(ae2[u], be[p], acce[u][p]);
        }
    }
    __syncthreads();
  }
  const float epsterm = (float)DIM * 1e-6f * 1e-6f;
  float sjl[5], rjl[5], sje[5], rje[5];
#pragma unroll
  for (int p = 0; p < 5; ++p) {
    int j = c0 + tx * 4 + p;
    int jj = j < BROWS ? j : (BROWS - 1);
    sjl[p] = s_l[jj]; rjl[p] = r_l[jj];
    sje[p] = s_e[jj]; rje[p] = r_e[jj];
  }
  float sum = 0.f;
#pragma unroll
  for (int u = 0; u < 8; ++u) {
    const int i = i0 + ty * 8 + u;
    if (i >= BROWS - 1) continue;
    const float sil = s_l[i], ril = r_l[i];
    const float sie = s_e[i], rie = r_e[i];
    float dl[5], de[5];
#pragma unroll
    for (int p = 0; p < 5; ++p) {
      const float sql = sil + sjl[p] - 2.f * accl[u][p] + 2e-6f * (ril - rjl[p]) + epsterm;
      dl[p] = sqrtf(fmaxf(sql, 0.f));
      const float sqe = sie + sje[p] - 2.f * acce[u][p] + 2e-6f * (rie - rje[p]) + epsterm;
      de[p] = sqrtf(fmaxf(sqe, 0.f));
    }
#pragma unroll
    for (int p = 0; p < 4; ++p) {
      const int j = c0 + tx * 4 + p;
      if (j < BROWS - 2) {
        const float a = dl[p] - dl[p + 1];
        const float b = de[p] - de[p + 1];
        const float coeff = (float)((a > 0.f) - (a < 0.f)) - (float)((b > 0.f) - (b < 0.f));
        sum += coeff * (de[p + 1] - de[p]);
      }
    }
  }
#pragma unroll
  for (int o = 32; o; o >>= 1) sum += __shfl_down(sum, o, 64);
  const int lane = tid & 63, wid = tid >> 6;
  if (lane == 0) sred[wid] = sum;
  __syncthreads();
  if (tid == 0) {
    const float scale = 1.0f / ((float)(BROWS - 1) * (float)(BROWS - 2));
    atomicAdd(out, (sred[0] + sred[1] + sred[2] + sred[3]) * scale);
  }
}

// ===========================================================================
extern "C" void kernel_launch(void* const* d_in, const int* in_sizes, int n_in,
                              void* d_out, int out_size, void* d_ws,
                              size_t ws_size, hipStream_t stream) {
  const float* low = (const float*)d_in[0];
  const float* emb = (const float*)d_in[1];
  float* out = (float*)d_out;

  const size_t ybytes = (size_t)BROWS * DIM * sizeof(__hip_bfloat16);  // 4 MB
  const size_t needed = 2 * ybytes + 4 * BROWS * sizeof(float);

  hipMemsetAsync(d_out, 0, sizeof(float), stream);

  if (ws_size >= needed) {
    __hip_bfloat16* Ylow = (__hip_bfloat16*)d_ws;
    __hip_bfloat16* Yemb = Ylow + (size_t)BROWS * DIM;
    float* s_l = (float*)(Yemb + (size_t)BROWS * DIM);
    float* r_l = s_l + BROWS;
    float* s_e = r_l + BROWS;
    float* r_e = s_e + BROWS;

    prep_kernel<<<BROWS, 256, 0, stream>>>(low, Ylow, s_l, r_l);
    prep_kernel<<<BROWS, 256, 0, stream>>>(emb, Yemb, s_e, r_e);
    fused_mfma_kernel<<<dim3(52, 32), 256, 0, stream>>>(
        Ylow, Yemb, s_l, r_l, s_e, r_e, out);
  } else {
    float* ws = (float*)d_ws;
    float* inv_l = ws;
    float* s_l = ws + 4096;
    float* r_l = ws + 8192;
    float* inv_e = ws + 12288;
    float* s_e = ws + 16384;
    float* r_e = ws + 20480;
    rowstats_kernel<<<BROWS, 256, 0, stream>>>(low, inv_l, s_l, r_l);
    rowstats_kernel<<<BROWS, 256, 0, stream>>>(emb, inv_e, s_e, r_e);
    fused_fp32_kernel<<<dim3(64, 32), 256, 0, stream>>>(
        low, emb, inv_l, s_l, r_l, inv_e, s_e, r_e, out);
  }
}

// Round 3
// 172.460 us; speedup vs baseline: 4.3879x; 1.0452x over previous
//
#include <hip/hip_runtime.h>
#include <hip/hip_bf16.h>
#include <math.h>

#define BROWS 4096
#define DIM   512

typedef float f32x4 __attribute__((ext_vector_type(4)));
typedef __bf16 bf16x8 __attribute__((ext_vector_type(8)));

// ---------------------------------------------------------------------------
// prep2: both matrices in one launch. Block b < 4096 -> low row b, else emb.
// Row L2-normalize -> bf16 Y (low rows 0..4095, emb rows 4096..8191),
// s = sum(y^2), r = sum(y). Block 0 thread 0 zeroes the output scalar.
// ---------------------------------------------------------------------------
__global__ __launch_bounds__(256) void prep2_kernel(
    const float* __restrict__ low, const float* __restrict__ emb,
    __hip_bfloat16* __restrict__ Y,
    float* __restrict__ s_l, float* __restrict__ r_l,
    float* __restrict__ s_e, float* __restrict__ r_e,
    float* __restrict__ out) {
  const int b = blockIdx.x;
  const int tid = threadIdx.x;
  const bool is_low = (b < BROWS);
  const int row = is_low ? b : (b - BROWS);
  const float* x = (is_low ? low : emb) + (size_t)row * DIM;

  if (b == 0 && tid == 0) out[0] = 0.f;

  const float2 v = ((const float2*)x)[tid];

  __shared__ float sredA[4];
  __shared__ float sredB[4];
  __shared__ float sbcast;

  float ss = v.x * v.x + v.y * v.y;
#pragma unroll
  for (int o = 32; o; o >>= 1) ss += __shfl_down(ss, o, 64);
  const int lane = tid & 63, wid = tid >> 6;
  if (lane == 0) sredA[wid] = ss;
  __syncthreads();
  if (tid == 0)
    sbcast = 1.0f / fmaxf(sqrtf(sredA[0] + sredA[1] + sredA[2] + sredA[3]), 1e-12f);
  __syncthreads();
  const float inv = sbcast;
  const float y0 = v.x * inv, y1 = v.y * inv;

  __hip_bfloat162 h;
  h.x = __float2bfloat16(y0);
  h.y = __float2bfloat16(y1);
  ((__hip_bfloat162*)(Y + (size_t)b * DIM))[tid] = h;

  float sv = y0 * y0 + y1 * y1;
  float rv = y0 + y1;
#pragma unroll
  for (int o = 32; o; o >>= 1) {
    sv += __shfl_down(sv, o, 64);
    rv += __shfl_down(rv, o, 64);
  }
  __syncthreads();
  if (lane == 0) { sredA[wid] = sv; sredB[wid] = rv; }
  __syncthreads();
  if (tid == 0) {
    float* s_out = is_low ? s_l : s_e;
    float* r_out = is_low ? r_l : r_e;
    s_out[row] = sredA[0] + sredA[1] + sredA[2] + sredA[3];
    r_out[row] = sredB[0] + sredB[1] + sredB[2] + sredB[3];
  }
}

// ---------------------------------------------------------------------------
// Fused MFMA kernel, round 3.
// Block = 4 waves. Block tile: 256 rows (wave w: rows i0+64w..+63) x 64 cols.
// Wave tile: 64x64 per matrix -> 4x4 accl + 4x4 acce (16x16 tiles).
// NPAIR = 63 pairs/block (col windows overlap by 1). Grid (65, 16).
// LDS per K32 stage: Alow[256][32] Aemb[256][32] Blow[64][32] Bemb[64][32]
//   = 2560 x 16B chunks, 40 KB; chunk c -> lds elem c*8 (linear).
// Staging: thread t owns chunks c = t + 256*s, s=0..9; global offsets
// precomputed once; K-loop adds k0. global_load_lds width=16,
// wave-uniform LDS base + lane*16 (chunk segments are 64-aligned).
// Frag reads: 1KB contiguous per wave-read (conflict-free).
// C frag mapping (m89/m91): col = lane&15, row = (lane>>4)*4 + reg.
// ---------------------------------------------------------------------------
#define AEMB_E 8192
#define BLOW_E 16384
#define BEMB_E 18432
#define YEMB_E 2097152   // 4096*512
#define NPAIR 63

__global__ __launch_bounds__(256, 2) void fused_mfma_kernel(
    const __hip_bfloat16* __restrict__ Y,   // [2*4096][512]: low rows then emb rows
    const float* __restrict__ s_l, const float* __restrict__ r_l,
    const float* __restrict__ s_e, const float* __restrict__ r_e,
    float* __restrict__ out) {
  __shared__ __align__(16) __hip_bfloat16 lds[20480];  // 40 KB
  __shared__ float sred[4];

  const int tid = threadIdx.x;
  const int lane = tid & 63;
  const int wid = tid >> 6;
  const int quad = lane >> 4;
  const int cpos = lane & 15;
  const int i0 = blockIdx.y * 256;
  const int c0 = blockIdx.x * NPAIR;

  // ---- precompute 10 staging offsets (elems into Y) ----
  int off[10];
#pragma unroll
  for (int s = 0; s < 10; ++s) {
    const int c = tid + 256 * s;
    int o;
    if (c < 1024)       o = (i0 + (c >> 2)) * DIM;                    // Alow
    else if (c < 2048)  o = YEMB_E + (i0 + ((c - 1024) >> 2)) * DIM;  // Aemb
    else if (c < 2304)  o = (c0 + ((c - 2048) >> 2)) * DIM;           // Blow
    else                o = YEMB_E + (c0 + ((c - 2304) >> 2)) * DIM;  // Bemb
    off[s] = o + (c & 3) * 8;
  }

  f32x4 accl[4][4], acce[4][4];
#pragma unroll
  for (int u = 0; u < 4; ++u)
#pragma unroll
    for (int v = 0; v < 4; ++v) {
      accl[u][v] = (f32x4)(0.f);
      acce[u][v] = (f32x4)(0.f);
    }

  const int fo = cpos * 32 + quad * 8;     // frag offset within a segment row-block
  const int ldsbase = wid * 512;           // elems; + s*2048 per slot

  for (int k0 = 0; k0 < DIM; k0 += 32) {
#pragma unroll
    for (int s = 0; s < 10; ++s) {
      __builtin_amdgcn_global_load_lds(
          (const __attribute__((address_space(1))) void*)(Y + off[s] + k0),
          (__attribute__((address_space(3))) void*)(lds + ldsbase + s * 2048),
          16, 0, 0);
    }
    __syncthreads();

    bf16x8 al[4], ae[4], bl[4], be[4];
#pragma unroll
    for (int u = 0; u < 4; ++u) {
      al[u] = *(const bf16x8*)&lds[(wid * 64 + 16 * u) * 32 + fo];
      ae[u] = *(const bf16x8*)&lds[AEMB_E + (wid * 64 + 16 * u) * 32 + fo];
    }
#pragma unroll
    for (int v = 0; v < 4; ++v) {
      bl[v] = *(const bf16x8*)&lds[BLOW_E + (16 * v) * 32 + fo];
      be[v] = *(const bf16x8*)&lds[BEMB_E + (16 * v) * 32 + fo];
    }
#pragma unroll
    for (int u = 0; u < 4; ++u)
#pragma unroll
      for (int v = 0; v < 4; ++v) {
        accl[u][v] = __builtin_amdgcn_mfma_f32_16x16x32_bf16(al[u], bl[v], accl[u][v], 0, 0, 0);
        acce[u][v] = __builtin_amdgcn_mfma_f32_16x16x32_bf16(ae[u], be[v], acce[u][v], 0, 0, 0);
      }
    __syncthreads();
  }

  // ---- epilogue ----
  const float epsterm = (float)DIM * 1e-6f * 1e-6f;
  float sjl[4], rjl[4], sje[4], rje[4];
#pragma unroll
  for (int v = 0; v < 4; ++v) {
    const int j = c0 + 16 * v + cpos;   // always < 4096 (c0 max 4032)
    sjl[v] = s_l[j]; rjl[v] = r_l[j];
    sje[v] = s_e[j]; rje[v] = r_e[j];
  }

  float sum = 0.f;
#pragma unroll
  for (int u = 0; u < 4; ++u) {
    const int ibase = i0 + wid * 64 + 16 * u + quad * 4;
#pragma unroll
    for (int r = 0; r < 4; ++r) {
      const int i = ibase + r;
      const float sil = s_l[i], ril = r_l[i];
      const float sie = s_e[i], rie = r_e[i];
      float dl[4], de[4];
#pragma unroll
      for (int v = 0; v < 4; ++v) {
        const float sql = sil + sjl[v] - 2.f * accl[u][v][r] +
                          2e-6f * (ril - rjl[v]) + epsterm;
        dl[v] = sqrtf(fmaxf(sql, 0.f));
        const float sqe = sie + sje[v] - 2.f * acce[u][v][r] +
                          2e-6f * (rie - rje[v]) + epsterm;
        de[v] = sqrtf(fmaxf(sqe, 0.f));
      }
      const bool rowok = (i <= BROWS - 2);
      const int srcin = (lane & 48) | ((cpos + 1) & 15);
#pragma unroll
      for (int v = 0; v < 4; ++v) {
        float dl2 = __shfl(dl[v], srcin, 64);
        float de2 = __shfl(de[v], srcin, 64);
        if (v < 3) {
          const float dlb = __shfl(dl[v + 1], lane & 48, 64);
          const float deb = __shfl(de[v + 1], lane & 48, 64);
          if (cpos == 15) { dl2 = dlb; de2 = deb; }
        }
        const int p = 16 * v + cpos;
        const int j = c0 + p;
        if (rowok && p < NPAIR && j <= BROWS - 3) {
          const float a = dl[v] - dl2;
          const float b = de[v] - de2;
          const float coeff = (float)((a > 0.f) - (a < 0.f)) -
                              (float)((b > 0.f) - (b < 0.f));
          sum += coeff * (de2 - de[v]);
        }
      }
    }
  }

#pragma unroll
  for (int o = 32; o; o >>= 1) sum += __shfl_down(sum, o, 64);
  if (lane == 0) sred[wid] = sum;
  __syncthreads();
  if (tid == 0) {
    const float scale = 1.0f / ((float)(BROWS - 1) * (float)(BROWS - 2));
    atomicAdd(out, (sred[0] + sred[1] + sred[2] + sred[3]) * scale);
  }
}

// ===========================================================================
extern "C" void kernel_launch(void* const* d_in, const int* in_sizes, int n_in,
                              void* d_out, int out_size, void* d_ws,
                              size_t ws_size, hipStream_t stream) {
  const float* low = (const float*)d_in[0];
  const float* emb = (const float*)d_in[1];
  float* out = (float*)d_out;

  // ws layout: Y (2*4096*512 bf16 = 8 MB), then s_l, r_l, s_e, r_e (4096 f32 each)
  __hip_bfloat16* Y = (__hip_bfloat16*)d_ws;
  float* s_l = (float*)(Y + 2 * (size_t)BROWS * DIM);
  float* r_l = s_l + BROWS;
  float* s_e = r_l + BROWS;
  float* r_e = s_e + BROWS;

  prep2_kernel<<<2 * BROWS, 256, 0, stream>>>(low, emb, Y, s_l, r_l, s_e, r_e, out);
  fused_mfma_kernel<<<dim3(65, 16), 256, 0, stream>>>(Y, s_l, r_l, s_e, r_e, out);
}